// Round 15
// baseline (83.432 us; speedup 1.0000x reference)
//
#include <hip/hip_runtime.h>
#include <hip/hip_bf16.h>
#if !__has_builtin(__builtin_amdgcn_cvt_pk_fp8_f32) || !__has_builtin(__builtin_amdgcn_cvt_pk_f32_fp8)
#include <hip/hip_fp8.h>
#endif

// ---------------- workspace layout (bytes); ws_size ~1 GB ----------------
#define CUR_OFF   0          // int cur[3]
#define SLOT_OFF  1024       // int slot_of_pos[65536]
#define POS_OFF   263168     // int posm[3][65536]
#define WSKU_OFF  1049600    // fp8 [512][384] (x64)
#define WURL_OFF  1246208    // fp8 [512][192] (x64, cols 160..192 zero)
#define WQRY_OFF  1344512    // fp8 [512][192]
#define WF8_OFF   2097152    // fp8 word table [100000][128] (x64) = 12.8 MB
#define XS_OFF    16777216   // fp8 rows, stride 384 B (+256 rows slack)
#define XU_OFF    50331648   // fp8 rows, stride 192 B
#define XQ_OFF    68157440   // fp8 rows, stride 192 B

#define NPOS      65536
#define OUT_MASK  33554432   // 65536*512
#define F8_SCALE  64.0f
#define INV4096   (1.0f / 4096.0f)

typedef __attribute__((ext_vector_type(4))) float f32x4;
typedef __attribute__((ext_vector_type(2))) float f32x2;
typedef __attribute__((ext_vector_type(2))) unsigned int u32x2;

__device__ __forceinline__ float2 ld2(const float* p) {
    return *reinterpret_cast<const float2*>(p);
}

// fp8 e4m3 (OCP) pack/unpack
__device__ __forceinline__ unsigned int pk2_f8(float a, float b) {
#if __has_builtin(__builtin_amdgcn_cvt_pk_fp8_f32)
    return __builtin_amdgcn_cvt_pk_fp8_f32(a, b, 0u, false);
#else
    __hip_fp8_e4m3 fa(a), fb(b);
    return (unsigned int)fa.__x | ((unsigned int)fb.__x << 8);
#endif
}
__device__ __forceinline__ unsigned int pk4_f8(float a, float b, float c, float d) {
#if __has_builtin(__builtin_amdgcn_cvt_pk_fp8_f32)
    unsigned int v = 0;
    v = __builtin_amdgcn_cvt_pk_fp8_f32(a, b, v, false);
    v = __builtin_amdgcn_cvt_pk_fp8_f32(c, d, v, true);
    return v;
#else
    return pk2_f8(a, b) | (pk2_f8(c, d) << 16);
#endif
}
__device__ __forceinline__ float2 upk2_f8(unsigned int u) {
#if __has_builtin(__builtin_amdgcn_cvt_pk_f32_fp8)
    f32x2 r = __builtin_amdgcn_cvt_pk_f32_fp8(u, false);
    return make_float2(r.x, r.y);
#else
    __hip_fp8_e4m3 fa, fb;
    fa.__x = (unsigned char)(u & 0xff);
    fb.__x = (unsigned char)((u >> 8) & 0xff);
    return make_float2((float)fa, (float)fb);
#endif
}
__device__ __forceinline__ float2 upk2_f8_hi(unsigned int u) {
#if __has_builtin(__builtin_amdgcn_cvt_pk_f32_fp8)
    f32x2 r = __builtin_amdgcn_cvt_pk_f32_fp8(u, true);   // bytes 2,3
    return make_float2(r.x, r.y);
#else
    return upk2_f8(u >> 16);
#endif
}
__device__ __forceinline__ void st_f8x2(unsigned char* d, float a, float b) {
    *reinterpret_cast<unsigned short*>(d) = (unsigned short)(pk2_f8(a, b) & 0xffffu);
}

#define AS1(p) ((const __attribute__((address_space(1))) void*)(p))
#define AS3(p) ((__attribute__((address_space(3))) void*)(p))

// ---- K1: word table f32->fp8(x64) + weights f32->fp8(x64) + cursor zero ----
// word_t is read-once streaming -> nontemporal loads keep L3 for hot data.
__global__ __launch_bounds__(256) void prep_k(const float* __restrict__ sw,
                                              const float* __restrict__ uw,
                                              const float* __restrict__ qw,
                                              const float* __restrict__ word_t,
                                              char* ws) {
    const int b = blockIdx.x, t = threadIdx.x;
    if (b < 6250) {
        size_t i = ((size_t)b * 256 + t) * 8;
        f32x4 v0 = __builtin_nontemporal_load(reinterpret_cast<const f32x4*>(word_t + i));
        f32x4 v1 = __builtin_nontemporal_load(reinterpret_cast<const f32x4*>(word_t + i + 4));
        u32x2 pk;
        pk.x = pk4_f8(v0.x * F8_SCALE, v0.y * F8_SCALE, v0.z * F8_SCALE, v0.w * F8_SCALE);
        pk.y = pk4_f8(v1.x * F8_SCALE, v1.y * F8_SCALE, v1.z * F8_SCALE, v1.w * F8_SCALE);
        *reinterpret_cast<u32x2*>((unsigned char*)(ws + WF8_OFF) + i) = pk;
        return;
    }
    int tt = (b - 6250) * 256 + t;   // 393216 total
    if (tt < 3) ((int*)(ws + CUR_OFF))[tt] = 0;
    if (tt < 196608) {
        ((unsigned char*)(ws + WSKU_OFF))[tt] =
            (unsigned char)(pk2_f8(sw[tt] * F8_SCALE, 0.f) & 0xffu);
    } else if (tt < 294912) {
        int i = tt - 196608; int n = i / 192, k = i % 192;
        ((unsigned char*)(ws + WURL_OFF))[i] = (k < 160)
            ? (unsigned char)(pk2_f8(uw[n * 160 + k] * F8_SCALE, 0.f) & 0xffu) : 0;
    } else {
        int i = tt - 294912; int n = i / 192, k = i % 192;
        ((unsigned char*)(ws + WQRY_OFF))[i] = (k < 160)
            ? (unsigned char)(pk2_f8(qw[n * 160 + k] * F8_SCALE, 0.f) & 0xffu) : 0;
    }
}

// ------ K2: classify + slot alloc + mask + pad-row zeroing ------------------
__global__ __launch_bounds__(256) void alloc_k(const int* __restrict__ et_a,
                                               float* __restrict__ out, char* ws) {
    __shared__ int s_wcnt[4][3];
    __shared__ int s_base[3];
    __shared__ int s_woff[4][3];
    __shared__ int s_et[256];
    const int t = threadIdx.x, lane = t & 63, wid = t >> 6;
    const int p0 = blockIdx.x * 256;
    int p = p0 + t;
    int et = et_a[p];
    s_et[t] = et;
    int br = (et >= 1 && et <= 3) ? 0 : (et == 4 ? 1 : (et == 5 ? 2 : -1));
    unsigned long long m0 = __ballot(br == 0);
    unsigned long long m1 = __ballot(br == 1);
    unsigned long long m2 = __ballot(br == 2);
    if (lane == 0) {
        s_wcnt[wid][0] = (int)__popcll(m0);
        s_wcnt[wid][1] = (int)__popcll(m1);
        s_wcnt[wid][2] = (int)__popcll(m2);
    }
    __syncthreads();
    if (t < 3) {
        int c0 = s_wcnt[0][t], c1 = s_wcnt[1][t], c2 = s_wcnt[2][t], c3 = s_wcnt[3][t];
        int tot = c0 + c1 + c2 + c3;
        s_base[t] = tot ? atomicAdd(&((int*)(ws + CUR_OFF))[t], tot) : 0;
        s_woff[0][t] = 0; s_woff[1][t] = c0; s_woff[2][t] = c0 + c1; s_woff[3][t] = c0 + c1 + c2;
    }
    __syncthreads();
    unsigned long long lt = (1ull << lane) - 1ull;
    int slot = -1;
    if (br == 0)      slot = s_base[0] + s_woff[wid][0] + (int)__popcll(m0 & lt);
    else if (br == 1) slot = s_base[1] + s_woff[wid][1] + (int)__popcll(m1 & lt);
    else if (br == 2) slot = s_base[2] + s_woff[wid][2] + (int)__popcll(m2 & lt);
    if (slot >= 0) ((int*)(ws + POS_OFF))[br * NPOS + slot] = p;
    __builtin_nontemporal_store((et == 0) ? 1.0f : 0.0f, &out[OUT_MASK + p]);
    for (int i = wid; i < 256; i += 4) {
        if (s_et[i] == 0) {
            float* orow = out + (size_t)(p0 + i) * 512;
            f32x4 z = {0.f, 0.f, 0.f, 0.f};
            __builtin_nontemporal_store(z, reinterpret_cast<f32x4*>(&orow[lane * 8]));
            __builtin_nontemporal_store(z, reinterpret_cast<f32x4*>(&orow[lane * 8 + 4]));
        }
    }
}

// ---- K3: build fp8 rows, SLOT-ORDERED, 16-lane groups (4 rows/wave) --------
__device__ __forceinline__ void wsum8_f8(const unsigned char* __restrict__ wt8,
                                         const int* __restrict__ wid_p, int l,
                                         float* s) {
    #pragma unroll
    for (int k = 0; k < 12; ++k) {
        int w = wid_p[k];
        u32x2 u = *reinterpret_cast<const u32x2*>(wt8 + (size_t)w * 128 + 8 * l);
        float2 a0 = upk2_f8(u.x), a1 = upk2_f8_hi(u.x);
        float2 b0 = upk2_f8(u.y), b1 = upk2_f8_hi(u.y);
        s[0] += a0.x; s[1] += a0.y; s[2] += a1.x; s[3] += a1.y;
        s[4] += b0.x; s[5] += b0.y; s[6] += b1.x; s[7] += b1.y;
    }
}

__global__ __launch_bounds__(256) void build_k(
    const float* __restrict__ ev_t,
    const float* __restrict__ sku_t,  const float* __restrict__ cat_t,
    const float* __restrict__ price_t,const float* __restrict__ url_t,
    const int* __restrict__ et_a,     const int* __restrict__ sku_id,
    const int* __restrict__ url_id,   const int* __restrict__ cat_id,
    const int* __restrict__ price_id, const int* __restrict__ word_id,
    char* ws)
{
    const int z = blockIdx.z;
    const int count = ((const int*)(ws + CUR_OFF))[z];
    const int slot0 = blockIdx.x * 16;
    if (slot0 >= count) return;
    const int t = threadIdx.x, lane = t & 63, wid = t >> 6;
    const int g = lane >> 4, l = lane & 15;
    const int slot = slot0 + wid * 4 + g;
    if (slot >= count) return;
    const int p = ((const int*)(ws + POS_OFF))[z * NPOS + slot];
    const unsigned char* wf8 = (const unsigned char*)(ws + WF8_OFF);
    const float inv = 1.0f / 12.0f;

    if (z == 0) {
        unsigned char* X = (unsigned char*)(ws + XS_OFF) + (size_t)slot * 384;
        const int et = et_a[p];
        float2 e = ld2(ev_t + et * 32 + 2 * l);
        st_f8x2(X + 2 * l, e.x * F8_SCALE, e.y * F8_SCALE);
        const float* sr = sku_t + (size_t)sku_id[p] * 128 + 8 * l;
        f32x4 s0 = *reinterpret_cast<const f32x4*>(sr);
        f32x4 s1 = *reinterpret_cast<const f32x4*>(sr + 4);
        u32x2 sp;
        sp.x = pk4_f8(s0.x * F8_SCALE, s0.y * F8_SCALE, s0.z * F8_SCALE, s0.w * F8_SCALE);
        sp.y = pk4_f8(s1.x * F8_SCALE, s1.y * F8_SCALE, s1.z * F8_SCALE, s1.w * F8_SCALE);
        *reinterpret_cast<u32x2*>(X + 32 + 8 * l) = sp;
        f32x4 c = *reinterpret_cast<const f32x4*>(cat_t + (size_t)cat_id[p] * 64 + 4 * l);
        *reinterpret_cast<unsigned int*>(X + 160 + 4 * l) =
            pk4_f8(c.x * F8_SCALE, c.y * F8_SCALE, c.z * F8_SCALE, c.w * F8_SCALE);
        float2 v = ld2(price_t + (size_t)price_id[p] * 32 + 2 * l);
        st_f8x2(X + 224 + 2 * l, v.x * F8_SCALE, v.y * F8_SCALE);
        float s[8] = {0.f, 0.f, 0.f, 0.f, 0.f, 0.f, 0.f, 0.f};
        wsum8_f8(wf8, word_id + (size_t)p * 12, l, s);
        u32x2 wp;
        wp.x = pk4_f8(s[0] * inv, s[1] * inv, s[2] * inv, s[3] * inv);
        wp.y = pk4_f8(s[4] * inv, s[5] * inv, s[6] * inv, s[7] * inv);
        *reinterpret_cast<u32x2*>(X + 256 + 8 * l) = wp;
    } else if (z == 1) {
        unsigned char* X = (unsigned char*)(ws + XU_OFF) + (size_t)slot * 192;
        const float* ur = url_t + (size_t)url_id[p] * 128 + 8 * l;
        f32x4 u0 = *reinterpret_cast<const f32x4*>(ur);
        f32x4 u1 = *reinterpret_cast<const f32x4*>(ur + 4);
        u32x2 up;
        up.x = pk4_f8(u0.x * F8_SCALE, u0.y * F8_SCALE, u0.z * F8_SCALE, u0.w * F8_SCALE);
        up.y = pk4_f8(u1.x * F8_SCALE, u1.y * F8_SCALE, u1.z * F8_SCALE, u1.w * F8_SCALE);
        *reinterpret_cast<u32x2*>(X + 8 * l) = up;
        float2 e = ld2(ev_t + 4 * 32 + 2 * l);
        st_f8x2(X + 128 + 2 * l, e.x * F8_SCALE, e.y * F8_SCALE);
        *reinterpret_cast<unsigned short*>(X + 160 + 2 * l) = 0;
    } else {
        unsigned char* X = (unsigned char*)(ws + XQ_OFF) + (size_t)slot * 192;
        float2 e = ld2(ev_t + 5 * 32 + 2 * l);
        st_f8x2(X + 2 * l, e.x * F8_SCALE, e.y * F8_SCALE);
        float s[8] = {0.f, 0.f, 0.f, 0.f, 0.f, 0.f, 0.f, 0.f};
        wsum8_f8(wf8, word_id + (size_t)p * 12, l, s);
        u32x2 wp;
        wp.x = pk4_f8(s[0] * inv, s[1] * inv, s[2] * inv, s[3] * inv);
        wp.y = pk4_f8(s[4] * inv, s[5] * inv, s[6] * inv, s[7] * inv);
        *reinterpret_cast<u32x2*>(X + 32 + 8 * l) = wp;
        *reinterpret_cast<unsigned short*>(X + 160 + 2 * l) = 0;
    }
}

// ---- K4: BM=256 A-once GEMM  out[pos]=relu(X*W^T/4096+b) -------------------
// 512 threads (8 waves: 4 row-groups x 2 col-groups), 256x128 tile per nc.
// A staged once (96/48 KB); B double-buffered; halved W re-reads vs BM=128.
__global__ __launch_bounds__(512, 1) void gemm2_k(
    const char* __restrict__ ws_c, const float* __restrict__ sku_b,
    const float* __restrict__ url_b, const float* __restrict__ qry_b,
    float* __restrict__ out)
{
    const int z = blockIdx.z;
    const int count = ((const int*)(ws_c + CUR_OFF))[z];
    const int nmt = (count + 255) >> 8;
    const int orig = blockIdx.x;
    if (orig >= nmt) return;
    const int q8 = nmt >> 3, r8 = nmt & 7;
    const int xcd = orig & 7, idx = orig >> 3;
    const int mt = (xcd < r8 ? xcd * (q8 + 1) : r8 * (q8 + 1) + (xcd - r8) * q8) + idx;
    const int row0 = mt * 256;

    const int* posm = (const int*)(ws_c + POS_OFF) + z * NPOS;
    const char* arena; const char* Wb; const float* bias; int astride;
    if (z == 0)      { arena = ws_c + XS_OFF; Wb = ws_c + WSKU_OFF; bias = sku_b; astride = 384; }
    else if (z == 1) { arena = ws_c + XU_OFF; Wb = ws_c + WURL_OFF; bias = url_b; astride = 192; }
    else             { arena = ws_c + XQ_OFF; Wb = ws_c + WQRY_OFF; bias = qry_b; astride = 192; }

    __shared__ char ldsA[98304];        // z=0: 3 x [256][128B]; z>0: [256][128B] + [256][64B]
    __shared__ char ldsB[2][16384];

    const int t = threadIdx.x, lane = t & 63, wid = t >> 6;
    const int wr = wid >> 1, wc = wid & 1;          // 4 x 2 waves
    const int r = lane & 15, q = lane >> 4;

    auto stageA_full = [&](int ktA, int koff) {     // 256 rows x 128 B
        #pragma unroll
        for (int i = 0; i < 4; ++i) {
            int row = i * 64 + (t >> 3);
            int sb  = (t & 7) ^ (row & 7);
            const char* ga = arena + (size_t)(row0 + row) * astride + koff + sb * 16;
            __builtin_amdgcn_global_load_lds(AS1(ga), AS3(&ldsA[ktA * 32768 + i * 8192 + t * 16]), 16, 0, 0);
        }
    };
    auto stageA_half = [&](int koff) {              // 256 rows x 64 B -> +32768
        #pragma unroll
        for (int i = 0; i < 2; ++i) {
            int row = i * 128 + (t >> 2);
            int sb  = (t & 3) ^ (row & 3);
            const char* ga = arena + (size_t)(row0 + row) * astride + koff + sb * 16;
            __builtin_amdgcn_global_load_lds(AS1(ga), AS3(&ldsA[32768 + i * 8192 + t * 16]), 16, 0, 0);
        }
    };
    auto stageB_full = [&](int buf, int nc, int koff) {  // 128 rows x 128 B
        #pragma unroll
        for (int i = 0; i < 2; ++i) {
            int row = i * 64 + (t >> 3);
            int sb  = (t & 7) ^ (row & 7);
            const char* gb = Wb + (size_t)(nc * 128 + row) * astride + koff + sb * 16;
            __builtin_amdgcn_global_load_lds(AS1(gb), AS3(&ldsB[buf][i * 8192 + t * 16]), 16, 0, 0);
        }
    };
    auto stageB_half = [&](int buf, int nc, int koff) {  // 128 rows x 64 B
        int row = t >> 2;
        int sb  = (t & 3) ^ (row & 3);
        const char* gb = Wb + (size_t)(nc * 128 + row) * astride + koff + sb * 16;
        __builtin_amdgcn_global_load_lds(AS1(gb), AS3(&ldsB[buf][t * 16]), 16, 0, 0);
    };

    if (z == 0) { stageA_full(0, 0); stageA_full(1, 128); stageA_full(2, 256); }
    else        { stageA_full(0, 0); stageA_half(128); }
    stageB_full(0, 0, 0);
    if (z == 0) stageB_full(1, 0, 128); else stageB_half(1, 0, 128);
    __syncthreads();

    int posr[16];
    #pragma unroll
    for (int m = 0; m < 4; ++m)
        #pragma unroll
        for (int j = 0; j < 4; ++j) {
            int gr = row0 + wr * 64 + m * 16 + q * 4 + j;
            posr[m * 4 + j] = (gr < count) ? posm[gr] : -1;
        }

    f32x4 acc[4][4];
    auto compA_full = [&](int ktA, int buf) {
        #pragma unroll
        for (int kk = 0; kk < 4; ++kk) {
            const int u  = kk * 2 + (q >> 1);
            const int wo = (q & 1) * 8;
            long af[4], bf[4];
            #pragma unroll
            for (int m = 0; m < 4; ++m) {
                int arow = wr * 64 + m * 16 + r;
                af[m] = *reinterpret_cast<const long*>(
                    &ldsA[ktA * 32768 + arow * 128 + ((u ^ (arow & 7)) << 4) + wo]);
            }
            #pragma unroll
            for (int n = 0; n < 4; ++n) {
                int brow = wc * 64 + n * 16 + r;
                bf[n] = *reinterpret_cast<const long*>(
                    &ldsB[buf][brow * 128 + ((u ^ (brow & 7)) << 4) + wo]);
            }
            #pragma unroll
            for (int m = 0; m < 4; ++m)
                #pragma unroll
                for (int n = 0; n < 4; ++n)
                    acc[m][n] = __builtin_amdgcn_mfma_f32_16x16x32_fp8_fp8(af[m], bf[n], acc[m][n], 0, 0, 0);
        }
    };
    auto compA_half = [&](int buf) {
        #pragma unroll
        for (int kk = 0; kk < 2; ++kk) {
            const int u  = kk * 2 + (q >> 1);
            const int wo = (q & 1) * 8;
            long af[4], bf[4];
            #pragma unroll
            for (int m = 0; m < 4; ++m) {
                int arow = wr * 64 + m * 16 + r;
                af[m] = *reinterpret_cast<const long*>(
                    &ldsA[32768 + arow * 64 + ((u ^ (arow & 3)) << 4) + wo]);
            }
            #pragma unroll
            for (int n = 0; n < 4; ++n) {
                int brow = wc * 64 + n * 16 + r;
                bf[n] = *reinterpret_cast<const long*>(
                    &ldsB[buf][brow * 64 + ((u ^ (brow & 3)) << 4) + wo]);
            }
            #pragma unroll
            for (int m = 0; m < 4; ++m)
                #pragma unroll
                for (int n = 0; n < 4; ++n)
                    acc[m][n] = __builtin_amdgcn_mfma_f32_16x16x32_fp8_fp8(af[m], bf[n], acc[m][n], 0, 0, 0);
        }
    };
    auto epilogue = [&](int nc) {
        float bv[4];
        #pragma unroll
        for (int n = 0; n < 4; ++n) bv[n] = bias[nc * 128 + wc * 64 + n * 16 + r];
        #pragma unroll
        for (int m = 0; m < 4; ++m)
            #pragma unroll
            for (int j = 0; j < 4; ++j) {
                int pos = posr[m * 4 + j];
                if (pos >= 0) {
                    float* orow = out + (size_t)pos * 512 + nc * 128 + wc * 64;
                    #pragma unroll
                    for (int n = 0; n < 4; ++n)
                        __builtin_nontemporal_store(
                            fmaxf(acc[m][n][j] * INV4096 + bv[n], 0.f), &orow[n * 16 + r]);
                }
            }
    };

    if (z == 0) {
        for (int nc = 0; nc < 4; ++nc) {
            #pragma unroll
            for (int m = 0; m < 4; ++m)
                #pragma unroll
                for (int n = 0; n < 4; ++n)
                    acc[m][n] = (f32x4){0.f, 0.f, 0.f, 0.f};
            #pragma unroll
            for (int kt = 0; kt < 3; ++kt) {
                int j = nc * 3 + kt, jn = j + 1;
                if (jn < 12) stageB_full(jn & 1, jn / 3, (jn % 3) * 128);
                compA_full(kt, j & 1);
                __syncthreads();
            }
            epilogue(nc);
        }
    } else {
        for (int nc = 0; nc < 4; ++nc) {
            #pragma unroll
            for (int m = 0; m < 4; ++m)
                #pragma unroll
                for (int n = 0; n < 4; ++n)
                    acc[m][n] = (f32x4){0.f, 0.f, 0.f, 0.f};
            #pragma unroll
            for (int kt = 0; kt < 2; ++kt) {
                int j = nc * 2 + kt, jn = j + 1;
                if (jn < 8) {
                    if ((jn & 1) == 0) stageB_full(jn & 1, jn / 2, 0);
                    else               stageB_half(jn & 1, jn / 2, 128);
                }
                if (kt == 0) compA_full(0, j & 1);
                else         compA_half(j & 1);
                __syncthreads();
            }
            epilogue(nc);
        }
    }
}

// ---------------- host ----------------
extern "C" void kernel_launch(void* const* d_in, const int* in_sizes, int n_in,
                              void* d_out, int out_size, void* d_ws, size_t ws_size,
                              hipStream_t stream) {
    const float* ev_t    = (const float*)d_in[0];
    const float* word_t  = (const float*)d_in[1];
    const float* sku_t   = (const float*)d_in[2];
    const float* cat_t   = (const float*)d_in[3];
    const float* price_t = (const float*)d_in[4];
    const float* url_t   = (const float*)d_in[5];
    const float* sku_w   = (const float*)d_in[6];
    const float* sku_b   = (const float*)d_in[7];
    const float* url_w   = (const float*)d_in[8];
    const float* url_b   = (const float*)d_in[9];
    const float* query_w = (const float*)d_in[10];
    const float* query_b = (const float*)d_in[11];
    const int* event_type = (const int*)d_in[12];
    const int* sku_id     = (const int*)d_in[13];
    const int* url_id     = (const int*)d_in[14];
    const int* cat_id     = (const int*)d_in[15];
    const int* price_id   = (const int*)d_in[16];
    const int* word_id    = (const int*)d_in[17];

    char*  ws  = (char*)d_ws;
    float* out = (float*)d_out;

    prep_k<<<7786, 256, 0, stream>>>(sku_w, url_w, query_w, word_t, ws);
    alloc_k<<<256, 256, 0, stream>>>(event_type, out, ws);
    dim3 gb(4096, 1, 3);
    build_k<<<gb, 256, 0, stream>>>(ev_t, sku_t, cat_t, price_t, url_t,
                                    event_type, sku_id, url_id, cat_id, price_id,
                                    word_id, ws);
    dim3 gg(256, 1, 3);
    gemm2_k<<<gg, 512, 0, stream>>>(ws, sku_b, url_b, query_b, out);
}

// Round 16
// 80.580 us; speedup vs baseline: 1.0354x; 1.0354x over previous
//
#include <hip/hip_runtime.h>
#include <hip/hip_bf16.h>
#if !__has_builtin(__builtin_amdgcn_cvt_pk_fp8_f32) || !__has_builtin(__builtin_amdgcn_cvt_pk_f32_fp8)
#include <hip/hip_fp8.h>
#endif

// ---------------- workspace layout (bytes); ws_size ~1 GB ----------------
#define CUR_OFF   0          // int cur[3]
#define SLOT_OFF  1024       // int slot_of_pos[65536]
#define POS_OFF   263168     // int posm[3][65536]
#define WSKU_OFF  1049600    // fp8 [512][384] (x64)
#define WURL_OFF  1246208    // fp8 [512][192] (x64, cols 160..192 zero)
#define WQRY_OFF  1344512    // fp8 [512][192]
#define WF8_OFF   2097152    // fp8 word table [100000][128] (x64) = 12.8 MB
#define XS_OFF    16777216   // fp8 rows, stride 384 B
#define XU_OFF    50331648   // fp8 rows, stride 192 B
#define XQ_OFF    68157440   // fp8 rows, stride 192 B

#define NPOS      65536
#define OUT_MASK  33554432   // 65536*512
#define F8_SCALE  64.0f
#define INV4096   (1.0f / 4096.0f)

typedef __attribute__((ext_vector_type(4))) float f32x4;
typedef __attribute__((ext_vector_type(2))) float f32x2;
typedef __attribute__((ext_vector_type(2))) unsigned int u32x2;

__device__ __forceinline__ float2 ld2(const float* p) {
    return *reinterpret_cast<const float2*>(p);
}

// fp8 e4m3 (OCP) pack/unpack
__device__ __forceinline__ unsigned int pk2_f8(float a, float b) {
#if __has_builtin(__builtin_amdgcn_cvt_pk_fp8_f32)
    return __builtin_amdgcn_cvt_pk_fp8_f32(a, b, 0u, false);
#else
    __hip_fp8_e4m3 fa(a), fb(b);
    return (unsigned int)fa.__x | ((unsigned int)fb.__x << 8);
#endif
}
__device__ __forceinline__ unsigned int pk4_f8(float a, float b, float c, float d) {
#if __has_builtin(__builtin_amdgcn_cvt_pk_fp8_f32)
    unsigned int v = 0;
    v = __builtin_amdgcn_cvt_pk_fp8_f32(a, b, v, false);
    v = __builtin_amdgcn_cvt_pk_fp8_f32(c, d, v, true);
    return v;
#else
    return pk2_f8(a, b) | (pk2_f8(c, d) << 16);
#endif
}
__device__ __forceinline__ float2 upk2_f8(unsigned int u) {
#if __has_builtin(__builtin_amdgcn_cvt_pk_f32_fp8)
    f32x2 r = __builtin_amdgcn_cvt_pk_f32_fp8(u, false);
    return make_float2(r.x, r.y);
#else
    __hip_fp8_e4m3 fa, fb;
    fa.__x = (unsigned char)(u & 0xff);
    fb.__x = (unsigned char)((u >> 8) & 0xff);
    return make_float2((float)fa, (float)fb);
#endif
}
__device__ __forceinline__ float2 upk2_f8_hi(unsigned int u) {
#if __has_builtin(__builtin_amdgcn_cvt_pk_f32_fp8)
    f32x2 r = __builtin_amdgcn_cvt_pk_f32_fp8(u, true);   // bytes 2,3
    return make_float2(r.x, r.y);
#else
    return upk2_f8(u >> 16);
#endif
}
__device__ __forceinline__ void st_f8x2(unsigned char* d, float a, float b) {
    *reinterpret_cast<unsigned short*>(d) = (unsigned short)(pk2_f8(a, b) & 0xffffu);
}

#define AS1(p) ((const __attribute__((address_space(1))) void*)(p))
#define AS3(p) ((__attribute__((address_space(3))) void*)(p))

// ---- K1: word table f32->fp8(x64) + weights f32->fp8(x64) + cursor zero ----
// word_t is read-once streaming -> nontemporal loads keep L3 for hot data.
__global__ __launch_bounds__(256) void prep_k(const float* __restrict__ sw,
                                              const float* __restrict__ uw,
                                              const float* __restrict__ qw,
                                              const float* __restrict__ word_t,
                                              char* ws) {
    const int b = blockIdx.x, t = threadIdx.x;
    if (b < 6250) {
        size_t i = ((size_t)b * 256 + t) * 8;
        f32x4 v0 = __builtin_nontemporal_load(reinterpret_cast<const f32x4*>(word_t + i));
        f32x4 v1 = __builtin_nontemporal_load(reinterpret_cast<const f32x4*>(word_t + i + 4));
        u32x2 pk;
        pk.x = pk4_f8(v0.x * F8_SCALE, v0.y * F8_SCALE, v0.z * F8_SCALE, v0.w * F8_SCALE);
        pk.y = pk4_f8(v1.x * F8_SCALE, v1.y * F8_SCALE, v1.z * F8_SCALE, v1.w * F8_SCALE);
        *reinterpret_cast<u32x2*>((unsigned char*)(ws + WF8_OFF) + i) = pk;
        return;
    }
    int tt = (b - 6250) * 256 + t;   // 393216 total
    if (tt < 3) ((int*)(ws + CUR_OFF))[tt] = 0;
    if (tt < 196608) {
        ((unsigned char*)(ws + WSKU_OFF))[tt] =
            (unsigned char)(pk2_f8(sw[tt] * F8_SCALE, 0.f) & 0xffu);
    } else if (tt < 294912) {
        int i = tt - 196608; int n = i / 192, k = i % 192;
        ((unsigned char*)(ws + WURL_OFF))[i] = (k < 160)
            ? (unsigned char)(pk2_f8(uw[n * 160 + k] * F8_SCALE, 0.f) & 0xffu) : 0;
    } else {
        int i = tt - 294912; int n = i / 192, k = i % 192;
        ((unsigned char*)(ws + WQRY_OFF))[i] = (k < 160)
            ? (unsigned char)(pk2_f8(qw[n * 160 + k] * F8_SCALE, 0.f) & 0xffu) : 0;
    }
}

// ------ K2: classify + slot alloc + mask + pad-row zeroing ------------------
__global__ __launch_bounds__(256) void alloc_k(const int* __restrict__ et_a,
                                               float* __restrict__ out, char* ws) {
    __shared__ int s_wcnt[4][3];
    __shared__ int s_base[3];
    __shared__ int s_woff[4][3];
    __shared__ int s_et[256];
    const int t = threadIdx.x, lane = t & 63, wid = t >> 6;
    const int p0 = blockIdx.x * 256;
    int p = p0 + t;
    int et = et_a[p];
    s_et[t] = et;
    int br = (et >= 1 && et <= 3) ? 0 : (et == 4 ? 1 : (et == 5 ? 2 : -1));
    unsigned long long m0 = __ballot(br == 0);
    unsigned long long m1 = __ballot(br == 1);
    unsigned long long m2 = __ballot(br == 2);
    if (lane == 0) {
        s_wcnt[wid][0] = (int)__popcll(m0);
        s_wcnt[wid][1] = (int)__popcll(m1);
        s_wcnt[wid][2] = (int)__popcll(m2);
    }
    __syncthreads();
    if (t < 3) {
        int c0 = s_wcnt[0][t], c1 = s_wcnt[1][t], c2 = s_wcnt[2][t], c3 = s_wcnt[3][t];
        int tot = c0 + c1 + c2 + c3;
        s_base[t] = tot ? atomicAdd(&((int*)(ws + CUR_OFF))[t], tot) : 0;
        s_woff[0][t] = 0; s_woff[1][t] = c0; s_woff[2][t] = c0 + c1; s_woff[3][t] = c0 + c1 + c2;
    }
    __syncthreads();
    unsigned long long lt = (1ull << lane) - 1ull;
    int slot = -1;
    if (br == 0)      slot = s_base[0] + s_woff[wid][0] + (int)__popcll(m0 & lt);
    else if (br == 1) slot = s_base[1] + s_woff[wid][1] + (int)__popcll(m1 & lt);
    else if (br == 2) slot = s_base[2] + s_woff[wid][2] + (int)__popcll(m2 & lt);
    if (slot >= 0) ((int*)(ws + POS_OFF))[br * NPOS + slot] = p;
    __builtin_nontemporal_store((et == 0) ? 1.0f : 0.0f, &out[OUT_MASK + p]);
    for (int i = wid; i < 256; i += 4) {
        if (s_et[i] == 0) {
            float* orow = out + (size_t)(p0 + i) * 512;
            f32x4 z = {0.f, 0.f, 0.f, 0.f};
            __builtin_nontemporal_store(z, reinterpret_cast<f32x4*>(&orow[lane * 8]));
            __builtin_nontemporal_store(z, reinterpret_cast<f32x4*>(&orow[lane * 8 + 4]));
        }
    }
}

// ---- K3: build fp8 rows, SLOT-ORDERED, 16-lane groups (4 rows/wave) --------
__device__ __forceinline__ void wsum8_f8(const unsigned char* __restrict__ wt8,
                                         const int* __restrict__ wid_p, int l,
                                         float* s) {
    #pragma unroll
    for (int k = 0; k < 12; ++k) {
        int w = wid_p[k];
        u32x2 u = *reinterpret_cast<const u32x2*>(wt8 + (size_t)w * 128 + 8 * l);
        float2 a0 = upk2_f8(u.x), a1 = upk2_f8_hi(u.x);
        float2 b0 = upk2_f8(u.y), b1 = upk2_f8_hi(u.y);
        s[0] += a0.x; s[1] += a0.y; s[2] += a1.x; s[3] += a1.y;
        s[4] += b0.x; s[5] += b0.y; s[6] += b1.x; s[7] += b1.y;
    }
}

__global__ __launch_bounds__(256) void build_k(
    const float* __restrict__ ev_t,
    const float* __restrict__ sku_t,  const float* __restrict__ cat_t,
    const float* __restrict__ price_t,const float* __restrict__ url_t,
    const int* __restrict__ et_a,     const int* __restrict__ sku_id,
    const int* __restrict__ url_id,   const int* __restrict__ cat_id,
    const int* __restrict__ price_id, const int* __restrict__ word_id,
    char* ws)
{
    const int z = blockIdx.z;
    const int count = ((const int*)(ws + CUR_OFF))[z];
    const int slot0 = blockIdx.x * 16;
    if (slot0 >= count) return;
    const int t = threadIdx.x, lane = t & 63, wid = t >> 6;
    const int g = lane >> 4, l = lane & 15;
    const int slot = slot0 + wid * 4 + g;
    if (slot >= count) return;
    const int p = ((const int*)(ws + POS_OFF))[z * NPOS + slot];
    const unsigned char* wf8 = (const unsigned char*)(ws + WF8_OFF);
    const float inv = 1.0f / 12.0f;

    if (z == 0) {
        unsigned char* X = (unsigned char*)(ws + XS_OFF) + (size_t)slot * 384;
        const int et = et_a[p];
        float2 e = ld2(ev_t + et * 32 + 2 * l);
        st_f8x2(X + 2 * l, e.x * F8_SCALE, e.y * F8_SCALE);
        const float* sr = sku_t + (size_t)sku_id[p] * 128 + 8 * l;
        f32x4 s0 = *reinterpret_cast<const f32x4*>(sr);
        f32x4 s1 = *reinterpret_cast<const f32x4*>(sr + 4);
        u32x2 sp;
        sp.x = pk4_f8(s0.x * F8_SCALE, s0.y * F8_SCALE, s0.z * F8_SCALE, s0.w * F8_SCALE);
        sp.y = pk4_f8(s1.x * F8_SCALE, s1.y * F8_SCALE, s1.z * F8_SCALE, s1.w * F8_SCALE);
        *reinterpret_cast<u32x2*>(X + 32 + 8 * l) = sp;
        f32x4 c = *reinterpret_cast<const f32x4*>(cat_t + (size_t)cat_id[p] * 64 + 4 * l);
        *reinterpret_cast<unsigned int*>(X + 160 + 4 * l) =
            pk4_f8(c.x * F8_SCALE, c.y * F8_SCALE, c.z * F8_SCALE, c.w * F8_SCALE);
        float2 v = ld2(price_t + (size_t)price_id[p] * 32 + 2 * l);
        st_f8x2(X + 224 + 2 * l, v.x * F8_SCALE, v.y * F8_SCALE);
        float s[8] = {0.f, 0.f, 0.f, 0.f, 0.f, 0.f, 0.f, 0.f};
        wsum8_f8(wf8, word_id + (size_t)p * 12, l, s);
        u32x2 wp;
        wp.x = pk4_f8(s[0] * inv, s[1] * inv, s[2] * inv, s[3] * inv);
        wp.y = pk4_f8(s[4] * inv, s[5] * inv, s[6] * inv, s[7] * inv);
        *reinterpret_cast<u32x2*>(X + 256 + 8 * l) = wp;
    } else if (z == 1) {
        unsigned char* X = (unsigned char*)(ws + XU_OFF) + (size_t)slot * 192;
        const float* ur = url_t + (size_t)url_id[p] * 128 + 8 * l;
        f32x4 u0 = *reinterpret_cast<const f32x4*>(ur);
        f32x4 u1 = *reinterpret_cast<const f32x4*>(ur + 4);
        u32x2 up;
        up.x = pk4_f8(u0.x * F8_SCALE, u0.y * F8_SCALE, u0.z * F8_SCALE, u0.w * F8_SCALE);
        up.y = pk4_f8(u1.x * F8_SCALE, u1.y * F8_SCALE, u1.z * F8_SCALE, u1.w * F8_SCALE);
        *reinterpret_cast<u32x2*>(X + 8 * l) = up;
        float2 e = ld2(ev_t + 4 * 32 + 2 * l);
        st_f8x2(X + 128 + 2 * l, e.x * F8_SCALE, e.y * F8_SCALE);
        *reinterpret_cast<unsigned short*>(X + 160 + 2 * l) = 0;
    } else {
        unsigned char* X = (unsigned char*)(ws + XQ_OFF) + (size_t)slot * 192;
        float2 e = ld2(ev_t + 5 * 32 + 2 * l);
        st_f8x2(X + 2 * l, e.x * F8_SCALE, e.y * F8_SCALE);
        float s[8] = {0.f, 0.f, 0.f, 0.f, 0.f, 0.f, 0.f, 0.f};
        wsum8_f8(wf8, word_id + (size_t)p * 12, l, s);
        u32x2 wp;
        wp.x = pk4_f8(s[0] * inv, s[1] * inv, s[2] * inv, s[3] * inv);
        wp.y = pk4_f8(s[4] * inv, s[5] * inv, s[6] * inv, s[7] * inv);
        *reinterpret_cast<u32x2*>(X + 32 + 8 * l) = wp;
        *reinterpret_cast<unsigned short*>(X + 160 + 2 * l) = 0;
    }
}

// ---- K4: A-once GEMM  out[pos]=relu(X*W^T/4096+b)  (R14 proven shape) ------
__global__ __launch_bounds__(256, 2) void gemm2_k(
    const char* __restrict__ ws_c, const float* __restrict__ sku_b,
    const float* __restrict__ url_b, const float* __restrict__ qry_b,
    float* __restrict__ out)
{
    const int z = blockIdx.z;
    const int count = ((const int*)(ws_c + CUR_OFF))[z];
    const int nmt = (count + 127) >> 7;
    const int orig = blockIdx.x;
    if (orig >= nmt) return;
    const int q8 = nmt >> 3, r8 = nmt & 7;
    const int xcd = orig & 7, idx = orig >> 3;
    const int mt = (xcd < r8 ? xcd * (q8 + 1) : r8 * (q8 + 1) + (xcd - r8) * q8) + idx;
    const int row0 = mt * 128;

    const int* posm = (const int*)(ws_c + POS_OFF) + z * NPOS;
    const char* arena; const char* Wb; const float* bias; int astride;
    if (z == 0)      { arena = ws_c + XS_OFF; Wb = ws_c + WSKU_OFF; bias = sku_b; astride = 384; }
    else if (z == 1) { arena = ws_c + XU_OFF; Wb = ws_c + WURL_OFF; bias = url_b; astride = 192; }
    else             { arena = ws_c + XQ_OFF; Wb = ws_c + WQRY_OFF; bias = qry_b; astride = 192; }

    __shared__ char ldsA[49152];
    __shared__ char ldsB[2][16384];

    const int t = threadIdx.x, lane = t & 63, wid = t >> 6;
    const int wr = wid >> 1, wc = wid & 1;
    const int r = lane & 15, q = lane >> 4;

    auto stageA_full = [&](int ktA, int koff) {
        #pragma unroll
        for (int i = 0; i < 4; ++i) {
            int row = i * 32 + (t >> 3);
            int sb  = (t & 7) ^ (row & 7);
            const char* ga = arena + (size_t)(row0 + row) * astride + koff + sb * 16;
            __builtin_amdgcn_global_load_lds(AS1(ga), AS3(&ldsA[ktA * 16384 + i * 4096 + t * 16]), 16, 0, 0);
        }
    };
    auto stageA_half = [&](int koff) {
        #pragma unroll
        for (int i = 0; i < 2; ++i) {
            int row = i * 64 + (t >> 2);
            int sb  = (t & 3) ^ (row & 3);
            const char* ga = arena + (size_t)(row0 + row) * astride + koff + sb * 16;
            __builtin_amdgcn_global_load_lds(AS1(ga), AS3(&ldsA[16384 + i * 4096 + t * 16]), 16, 0, 0);
        }
    };
    auto stageB_full = [&](int buf, int nc, int koff) {
        #pragma unroll
        for (int i = 0; i < 4; ++i) {
            int row = i * 32 + (t >> 3);
            int sb  = (t & 7) ^ (row & 7);
            const char* gb = Wb + (size_t)(nc * 128 + row) * astride + koff + sb * 16;
            __builtin_amdgcn_global_load_lds(AS1(gb), AS3(&ldsB[buf][i * 4096 + t * 16]), 16, 0, 0);
        }
    };
    auto stageB_half = [&](int buf, int nc, int koff) {
        #pragma unroll
        for (int i = 0; i < 2; ++i) {
            int row = i * 64 + (t >> 2);
            int sb  = (t & 3) ^ (row & 3);
            const char* gb = Wb + (size_t)(nc * 128 + row) * astride + koff + sb * 16;
            __builtin_amdgcn_global_load_lds(AS1(gb), AS3(&ldsB[buf][i * 4096 + t * 16]), 16, 0, 0);
        }
    };

    if (z == 0) { stageA_full(0, 0); stageA_full(1, 128); stageA_full(2, 256); }
    else        { stageA_full(0, 0); stageA_half(128); }
    stageB_full(0, 0, 0);
    if (z == 0) stageB_full(1, 0, 128); else stageB_half(1, 0, 128);
    __syncthreads();

    int posr[16];
    #pragma unroll
    for (int m = 0; m < 4; ++m)
        #pragma unroll
        for (int j = 0; j < 4; ++j) {
            int gr = row0 + wr * 64 + m * 16 + q * 4 + j;
            posr[m * 4 + j] = (gr < count) ? posm[gr] : -1;
        }

    f32x4 acc[4][4];
    auto compA_full = [&](int ktA, int buf) {
        #pragma unroll
        for (int kk = 0; kk < 4; ++kk) {
            const int u  = kk * 2 + (q >> 1);
            const int wo = (q & 1) * 8;
            long af[4], bf[4];
            #pragma unroll
            for (int m = 0; m < 4; ++m) {
                int arow = wr * 64 + m * 16 + r;
                af[m] = *reinterpret_cast<const long*>(
                    &ldsA[ktA * 16384 + arow * 128 + ((u ^ (arow & 7)) << 4) + wo]);
            }
            #pragma unroll
            for (int n = 0; n < 4; ++n) {
                int brow = wc * 64 + n * 16 + r;
                bf[n] = *reinterpret_cast<const long*>(
                    &ldsB[buf][brow * 128 + ((u ^ (brow & 7)) << 4) + wo]);
            }
            #pragma unroll
            for (int m = 0; m < 4; ++m)
                #pragma unroll
                for (int n = 0; n < 4; ++n)
                    acc[m][n] = __builtin_amdgcn_mfma_f32_16x16x32_fp8_fp8(af[m], bf[n], acc[m][n], 0, 0, 0);
        }
    };
    auto compA_half = [&](int buf) {
        #pragma unroll
        for (int kk = 0; kk < 2; ++kk) {
            const int u  = kk * 2 + (q >> 1);
            const int wo = (q & 1) * 8;
            long af[4], bf[4];
            #pragma unroll
            for (int m = 0; m < 4; ++m) {
                int arow = wr * 64 + m * 16 + r;
                af[m] = *reinterpret_cast<const long*>(
                    &ldsA[16384 + arow * 64 + ((u ^ (arow & 3)) << 4) + wo]);
            }
            #pragma unroll
            for (int n = 0; n < 4; ++n) {
                int brow = wc * 64 + n * 16 + r;
                bf[n] = *reinterpret_cast<const long*>(
                    &ldsB[buf][brow * 64 + ((u ^ (brow & 3)) << 4) + wo]);
            }
            #pragma unroll
            for (int m = 0; m < 4; ++m)
                #pragma unroll
                for (int n = 0; n < 4; ++n)
                    acc[m][n] = __builtin_amdgcn_mfma_f32_16x16x32_fp8_fp8(af[m], bf[n], acc[m][n], 0, 0, 0);
        }
    };
    auto epilogue = [&](int nc) {
        float bv[4];
        #pragma unroll
        for (int n = 0; n < 4; ++n) bv[n] = bias[nc * 128 + wc * 64 + n * 16 + r];
        #pragma unroll
        for (int m = 0; m < 4; ++m)
            #pragma unroll
            for (int j = 0; j < 4; ++j) {
                int pos = posr[m * 4 + j];
                if (pos >= 0) {
                    float* orow = out + (size_t)pos * 512 + nc * 128 + wc * 64;
                    #pragma unroll
                    for (int n = 0; n < 4; ++n)
                        __builtin_nontemporal_store(
                            fmaxf(acc[m][n][j] * INV4096 + bv[n], 0.f), &orow[n * 16 + r]);
                }
            }
    };

    if (z == 0) {
        for (int nc = 0; nc < 4; ++nc) {
            #pragma unroll
            for (int m = 0; m < 4; ++m)
                #pragma unroll
                for (int n = 0; n < 4; ++n)
                    acc[m][n] = (f32x4){0.f, 0.f, 0.f, 0.f};
            #pragma unroll
            for (int kt = 0; kt < 3; ++kt) {
                int j = nc * 3 + kt, jn = j + 1;
                if (jn < 12) stageB_full(jn & 1, jn / 3, (jn % 3) * 128);
                compA_full(kt, j & 1);
                __syncthreads();
            }
            epilogue(nc);
        }
    } else {
        for (int nc = 0; nc < 4; ++nc) {
            #pragma unroll
            for (int m = 0; m < 4; ++m)
                #pragma unroll
                for (int n = 0; n < 4; ++n)
                    acc[m][n] = (f32x4){0.f, 0.f, 0.f, 0.f};
            #pragma unroll
            for (int kt = 0; kt < 2; ++kt) {
                int j = nc * 2 + kt, jn = j + 1;
                if (jn < 8) {
                    if ((jn & 1) == 0) stageB_full(jn & 1, jn / 2, 0);
                    else               stageB_half(jn & 1, jn / 2, 128);
                }
                if (kt == 0) compA_full(0, j & 1);
                else         compA_half(j & 1);
                __syncthreads();
            }
            epilogue(nc);
        }
    }
}

// ---------------- host ----------------
extern "C" void kernel_launch(void* const* d_in, const int* in_sizes, int n_in,
                              void* d_out, int out_size, void* d_ws, size_t ws_size,
                              hipStream_t stream) {
    const float* ev_t    = (const float*)d_in[0];
    const float* word_t  = (const float*)d_in[1];
    const float* sku_t   = (const float*)d_in[2];
    const float* cat_t   = (const float*)d_in[3];
    const float* price_t = (const float*)d_in[4];
    const float* url_t   = (const float*)d_in[5];
    const float* sku_w   = (const float*)d_in[6];
    const float* sku_b   = (const float*)d_in[7];
    const float* url_w   = (const float*)d_in[8];
    const float* url_b   = (const float*)d_in[9];
    const float* query_w = (const float*)d_in[10];
    const float* query_b = (const float*)d_in[11];
    const int* event_type = (const int*)d_in[12];
    const int* sku_id     = (const int*)d_in[13];
    const int* url_id     = (const int*)d_in[14];
    const int* cat_id     = (const int*)d_in[15];
    const int* price_id   = (const int*)d_in[16];
    const int* word_id    = (const int*)d_in[17];

    char*  ws  = (char*)d_ws;
    float* out = (float*)d_out;

    prep_k<<<7786, 256, 0, stream>>>(sku_w, url_w, query_w, word_t, ws);
    alloc_k<<<256, 256, 0, stream>>>(event_type, out, ws);
    dim3 gb(4096, 1, 3);
    build_k<<<gb, 256, 0, stream>>>(ev_t, sku_t, cat_t, price_t, url_t,
                                    event_type, sku_id, url_id, cat_id, price_id,
                                    word_id, ws);
    dim3 gg(512, 1, 3);
    gemm2_k<<<gg, 256, 0, stream>>>(ws, sku_b, url_b, query_b, out);
}

// Round 17
// 76.221 us; speedup vs baseline: 1.0946x; 1.0572x over previous
//
#include <hip/hip_runtime.h>
#include <hip/hip_bf16.h>
#if !__has_builtin(__builtin_amdgcn_cvt_pk_fp8_f32) || !__has_builtin(__builtin_amdgcn_cvt_pk_f32_fp8)
#include <hip/hip_fp8.h>
#endif

// ---------------- workspace layout (bytes); ws_size ~1 GB ----------------
#define CUR_OFF   0          // int cur[3]
#define SLOT_OFF  1024       // int slot_of_pos[65536]
#define POS_OFF   263168     // int posm[3][65536]
#define WSKU_OFF  1049600    // fp8 [512][384] (x64)
#define WURL_OFF  1246208    // fp8 [512][192] (x64, cols 160..192 zero)
#define WQRY_OFF  1344512    // fp8 [512][192]
#define WF8_OFF   2097152    // fp8 word table [100000][128] (x64) = 12.8 MB
#define XS_OFF    16777216   // fp8 rows, stride 384 B
#define XU_OFF    50331648   // fp8 rows, stride 192 B
#define XQ_OFF    68157440   // fp8 rows, stride 192 B

#define NPOS      65536
#define OUT_MASK  33554432   // 65536*512
#define F8_SCALE  64.0f
#define INV4096   (1.0f / 4096.0f)

typedef __attribute__((ext_vector_type(4))) float f32x4;
typedef __attribute__((ext_vector_type(2))) float f32x2;
typedef __attribute__((ext_vector_type(2))) unsigned int u32x2;

__device__ __forceinline__ float2 ld2(const float* p) {
    return *reinterpret_cast<const float2*>(p);
}

// fp8 e4m3 (OCP) pack/unpack
__device__ __forceinline__ unsigned int pk2_f8(float a, float b) {
#if __has_builtin(__builtin_amdgcn_cvt_pk_fp8_f32)
    return __builtin_amdgcn_cvt_pk_fp8_f32(a, b, 0u, false);
#else
    __hip_fp8_e4m3 fa(a), fb(b);
    return (unsigned int)fa.__x | ((unsigned int)fb.__x << 8);
#endif
}
__device__ __forceinline__ unsigned int pk4_f8(float a, float b, float c, float d) {
#if __has_builtin(__builtin_amdgcn_cvt_pk_fp8_f32)
    unsigned int v = 0;
    v = __builtin_amdgcn_cvt_pk_fp8_f32(a, b, v, false);
    v = __builtin_amdgcn_cvt_pk_fp8_f32(c, d, v, true);
    return v;
#else
    return pk2_f8(a, b) | (pk2_f8(c, d) << 16);
#endif
}
__device__ __forceinline__ float2 upk2_f8(unsigned int u) {
#if __has_builtin(__builtin_amdgcn_cvt_pk_f32_fp8)
    f32x2 r = __builtin_amdgcn_cvt_pk_f32_fp8(u, false);
    return make_float2(r.x, r.y);
#else
    __hip_fp8_e4m3 fa, fb;
    fa.__x = (unsigned char)(u & 0xff);
    fb.__x = (unsigned char)((u >> 8) & 0xff);
    return make_float2((float)fa, (float)fb);
#endif
}
__device__ __forceinline__ float2 upk2_f8_hi(unsigned int u) {
#if __has_builtin(__builtin_amdgcn_cvt_pk_f32_fp8)
    f32x2 r = __builtin_amdgcn_cvt_pk_f32_fp8(u, true);   // bytes 2,3
    return make_float2(r.x, r.y);
#else
    return upk2_f8(u >> 16);
#endif
}
__device__ __forceinline__ void st_f8x2(unsigned char* d, float a, float b) {
    *reinterpret_cast<unsigned short*>(d) = (unsigned short)(pk2_f8(a, b) & 0xffffu);
}

#define AS1(p) ((const __attribute__((address_space(1))) void*)(p))
#define AS3(p) ((__attribute__((address_space(3))) void*)(p))

// ---- K1: word table f32->fp8(x64) + weights f32->fp8(x64) + cursor zero ----
__global__ __launch_bounds__(256) void prep_k(const float* __restrict__ sw,
                                              const float* __restrict__ uw,
                                              const float* __restrict__ qw,
                                              const float* __restrict__ word_t,
                                              char* ws) {
    const int b = blockIdx.x, t = threadIdx.x;
    if (b < 6250) {
        size_t i = ((size_t)b * 256 + t) * 8;
        f32x4 v0 = *reinterpret_cast<const f32x4*>(word_t + i);
        f32x4 v1 = *reinterpret_cast<const f32x4*>(word_t + i + 4);
        u32x2 pk;
        pk.x = pk4_f8(v0.x * F8_SCALE, v0.y * F8_SCALE, v0.z * F8_SCALE, v0.w * F8_SCALE);
        pk.y = pk4_f8(v1.x * F8_SCALE, v1.y * F8_SCALE, v1.z * F8_SCALE, v1.w * F8_SCALE);
        *reinterpret_cast<u32x2*>((unsigned char*)(ws + WF8_OFF) + i) = pk;
        return;
    }
    int tt = (b - 6250) * 256 + t;   // 393216 total
    if (tt < 3) ((int*)(ws + CUR_OFF))[tt] = 0;
    if (tt < 196608) {
        ((unsigned char*)(ws + WSKU_OFF))[tt] =
            (unsigned char)(pk2_f8(sw[tt] * F8_SCALE, 0.f) & 0xffu);
    } else if (tt < 294912) {
        int i = tt - 196608; int n = i / 192, k = i % 192;
        ((unsigned char*)(ws + WURL_OFF))[i] = (k < 160)
            ? (unsigned char)(pk2_f8(uw[n * 160 + k] * F8_SCALE, 0.f) & 0xffu) : 0;
    } else {
        int i = tt - 294912; int n = i / 192, k = i % 192;
        ((unsigned char*)(ws + WQRY_OFF))[i] = (k < 160)
            ? (unsigned char)(pk2_f8(qw[n * 160 + k] * F8_SCALE, 0.f) & 0xffu) : 0;
    }
}

// ------ K2: classify + slot alloc + mask + pad-row zeroing ------------------
__global__ __launch_bounds__(256) void alloc_k(const int* __restrict__ et_a,
                                               float* __restrict__ out, char* ws) {
    __shared__ int s_wcnt[4][3];
    __shared__ int s_base[3];
    __shared__ int s_woff[4][3];
    __shared__ int s_et[256];
    const int t = threadIdx.x, lane = t & 63, wid = t >> 6;
    const int p0 = blockIdx.x * 256;
    int p = p0 + t;
    int et = et_a[p];
    s_et[t] = et;
    int br = (et >= 1 && et <= 3) ? 0 : (et == 4 ? 1 : (et == 5 ? 2 : -1));
    unsigned long long m0 = __ballot(br == 0);
    unsigned long long m1 = __ballot(br == 1);
    unsigned long long m2 = __ballot(br == 2);
    if (lane == 0) {
        s_wcnt[wid][0] = (int)__popcll(m0);
        s_wcnt[wid][1] = (int)__popcll(m1);
        s_wcnt[wid][2] = (int)__popcll(m2);
    }
    __syncthreads();
    if (t < 3) {
        int c0 = s_wcnt[0][t], c1 = s_wcnt[1][t], c2 = s_wcnt[2][t], c3 = s_wcnt[3][t];
        int tot = c0 + c1 + c2 + c3;
        s_base[t] = tot ? atomicAdd(&((int*)(ws + CUR_OFF))[t], tot) : 0;
        s_woff[0][t] = 0; s_woff[1][t] = c0; s_woff[2][t] = c0 + c1; s_woff[3][t] = c0 + c1 + c2;
    }
    __syncthreads();
    unsigned long long lt = (1ull << lane) - 1ull;
    int slot = -1;
    if (br == 0)      slot = s_base[0] + s_woff[wid][0] + (int)__popcll(m0 & lt);
    else if (br == 1) slot = s_base[1] + s_woff[wid][1] + (int)__popcll(m1 & lt);
    else if (br == 2) slot = s_base[2] + s_woff[wid][2] + (int)__popcll(m2 & lt);
    if (slot >= 0) ((int*)(ws + POS_OFF))[br * NPOS + slot] = p;
    __builtin_nontemporal_store((et == 0) ? 1.0f : 0.0f, &out[OUT_MASK + p]);
    for (int i = wid; i < 256; i += 4) {
        if (s_et[i] == 0) {
            float* orow = out + (size_t)(p0 + i) * 512;
            f32x4 z = {0.f, 0.f, 0.f, 0.f};
            __builtin_nontemporal_store(z, reinterpret_cast<f32x4*>(&orow[lane * 8]));
            __builtin_nontemporal_store(z, reinterpret_cast<f32x4*>(&orow[lane * 8 + 4]));
        }
    }
}

// ---- K3: build fp8 rows, SLOT-ORDERED, 16-lane groups (4 rows/wave) --------
__device__ __forceinline__ void wsum8_f8(const unsigned char* __restrict__ wt8,
                                         const int* __restrict__ wid_p, int l,
                                         float* s) {
    #pragma unroll
    for (int k = 0; k < 12; ++k) {
        int w = wid_p[k];
        u32x2 u = *reinterpret_cast<const u32x2*>(wt8 + (size_t)w * 128 + 8 * l);
        float2 a0 = upk2_f8(u.x), a1 = upk2_f8_hi(u.x);
        float2 b0 = upk2_f8(u.y), b1 = upk2_f8_hi(u.y);
        s[0] += a0.x; s[1] += a0.y; s[2] += a1.x; s[3] += a1.y;
        s[4] += b0.x; s[5] += b0.y; s[6] += b1.x; s[7] += b1.y;
    }
}

__global__ __launch_bounds__(256) void build_k(
    const float* __restrict__ ev_t,
    const float* __restrict__ sku_t,  const float* __restrict__ cat_t,
    const float* __restrict__ price_t,const float* __restrict__ url_t,
    const int* __restrict__ et_a,     const int* __restrict__ sku_id,
    const int* __restrict__ url_id,   const int* __restrict__ cat_id,
    const int* __restrict__ price_id, const int* __restrict__ word_id,
    char* ws)
{
    const int z = blockIdx.z;
    const int count = ((const int*)(ws + CUR_OFF))[z];
    const int slot0 = blockIdx.x * 16;
    if (slot0 >= count) return;
    const int t = threadIdx.x, lane = t & 63, wid = t >> 6;
    const int g = lane >> 4, l = lane & 15;
    const int slot = slot0 + wid * 4 + g;
    if (slot >= count) return;
    const int p = ((const int*)(ws + POS_OFF))[z * NPOS + slot];
    const unsigned char* wf8 = (const unsigned char*)(ws + WF8_OFF);
    const float inv = 1.0f / 12.0f;

    if (z == 0) {
        unsigned char* X = (unsigned char*)(ws + XS_OFF) + (size_t)slot * 384;
        const int et = et_a[p];
        float2 e = ld2(ev_t + et * 32 + 2 * l);
        st_f8x2(X + 2 * l, e.x * F8_SCALE, e.y * F8_SCALE);
        const float* sr = sku_t + (size_t)sku_id[p] * 128 + 8 * l;
        f32x4 s0 = *reinterpret_cast<const f32x4*>(sr);
        f32x4 s1 = *reinterpret_cast<const f32x4*>(sr + 4);
        u32x2 sp;
        sp.x = pk4_f8(s0.x * F8_SCALE, s0.y * F8_SCALE, s0.z * F8_SCALE, s0.w * F8_SCALE);
        sp.y = pk4_f8(s1.x * F8_SCALE, s1.y * F8_SCALE, s1.z * F8_SCALE, s1.w * F8_SCALE);
        *reinterpret_cast<u32x2*>(X + 32 + 8 * l) = sp;
        f32x4 c = *reinterpret_cast<const f32x4*>(cat_t + (size_t)cat_id[p] * 64 + 4 * l);
        *reinterpret_cast<unsigned int*>(X + 160 + 4 * l) =
            pk4_f8(c.x * F8_SCALE, c.y * F8_SCALE, c.z * F8_SCALE, c.w * F8_SCALE);
        float2 v = ld2(price_t + (size_t)price_id[p] * 32 + 2 * l);
        st_f8x2(X + 224 + 2 * l, v.x * F8_SCALE, v.y * F8_SCALE);
        float s[8] = {0.f, 0.f, 0.f, 0.f, 0.f, 0.f, 0.f, 0.f};
        wsum8_f8(wf8, word_id + (size_t)p * 12, l, s);
        u32x2 wp;
        wp.x = pk4_f8(s[0] * inv, s[1] * inv, s[2] * inv, s[3] * inv);
        wp.y = pk4_f8(s[4] * inv, s[5] * inv, s[6] * inv, s[7] * inv);
        *reinterpret_cast<u32x2*>(X + 256 + 8 * l) = wp;
    } else if (z == 1) {
        unsigned char* X = (unsigned char*)(ws + XU_OFF) + (size_t)slot * 192;
        const float* ur = url_t + (size_t)url_id[p] * 128 + 8 * l;
        f32x4 u0 = *reinterpret_cast<const f32x4*>(ur);
        f32x4 u1 = *reinterpret_cast<const f32x4*>(ur + 4);
        u32x2 up;
        up.x = pk4_f8(u0.x * F8_SCALE, u0.y * F8_SCALE, u0.z * F8_SCALE, u0.w * F8_SCALE);
        up.y = pk4_f8(u1.x * F8_SCALE, u1.y * F8_SCALE, u1.z * F8_SCALE, u1.w * F8_SCALE);
        *reinterpret_cast<u32x2*>(X + 8 * l) = up;
        float2 e = ld2(ev_t + 4 * 32 + 2 * l);
        st_f8x2(X + 128 + 2 * l, e.x * F8_SCALE, e.y * F8_SCALE);
        *reinterpret_cast<unsigned short*>(X + 160 + 2 * l) = 0;
    } else {
        unsigned char* X = (unsigned char*)(ws + XQ_OFF) + (size_t)slot * 192;
        float2 e = ld2(ev_t + 5 * 32 + 2 * l);
        st_f8x2(X + 2 * l, e.x * F8_SCALE, e.y * F8_SCALE);
        float s[8] = {0.f, 0.f, 0.f, 0.f, 0.f, 0.f, 0.f, 0.f};
        wsum8_f8(wf8, word_id + (size_t)p * 12, l, s);
        u32x2 wp;
        wp.x = pk4_f8(s[0] * inv, s[1] * inv, s[2] * inv, s[3] * inv);
        wp.y = pk4_f8(s[4] * inv, s[5] * inv, s[6] * inv, s[7] * inv);
        *reinterpret_cast<u32x2*>(X + 32 + 8 * l) = wp;
        *reinterpret_cast<unsigned short*>(X + 160 + 2 * l) = 0;
    }
}

// ---- K4: A-once GEMM  out[pos]=relu(X*W^T/4096+b)  (R14 proven shape) ------
__global__ __launch_bounds__(256, 2) void gemm2_k(
    const char* __restrict__ ws_c, const float* __restrict__ sku_b,
    const float* __restrict__ url_b, const float* __restrict__ qry_b,
    float* __restrict__ out)
{
    const int z = blockIdx.z;
    const int count = ((const int*)(ws_c + CUR_OFF))[z];
    const int nmt = (count + 127) >> 7;
    const int orig = blockIdx.x;
    if (orig >= nmt) return;
    const int q8 = nmt >> 3, r8 = nmt & 7;
    const int xcd = orig & 7, idx = orig >> 3;
    const int mt = (xcd < r8 ? xcd * (q8 + 1) : r8 * (q8 + 1) + (xcd - r8) * q8) + idx;
    const int row0 = mt * 128;

    const int* posm = (const int*)(ws_c + POS_OFF) + z * NPOS;
    const char* arena; const char* Wb; const float* bias; int astride;
    if (z == 0)      { arena = ws_c + XS_OFF; Wb = ws_c + WSKU_OFF; bias = sku_b; astride = 384; }
    else if (z == 1) { arena = ws_c + XU_OFF; Wb = ws_c + WURL_OFF; bias = url_b; astride = 192; }
    else             { arena = ws_c + XQ_OFF; Wb = ws_c + WQRY_OFF; bias = qry_b; astride = 192; }

    __shared__ char ldsA[49152];
    __shared__ char ldsB[2][16384];

    const int t = threadIdx.x, lane = t & 63, wid = t >> 6;
    const int wr = wid >> 1, wc = wid & 1;
    const int r = lane & 15, q = lane >> 4;

    auto stageA_full = [&](int ktA, int koff) {
        #pragma unroll
        for (int i = 0; i < 4; ++i) {
            int row = i * 32 + (t >> 3);
            int sb  = (t & 7) ^ (row & 7);
            const char* ga = arena + (size_t)(row0 + row) * astride + koff + sb * 16;
            __builtin_amdgcn_global_load_lds(AS1(ga), AS3(&ldsA[ktA * 16384 + i * 4096 + t * 16]), 16, 0, 0);
        }
    };
    auto stageA_half = [&](int koff) {
        #pragma unroll
        for (int i = 0; i < 2; ++i) {
            int row = i * 64 + (t >> 2);
            int sb  = (t & 3) ^ (row & 3);
            const char* ga = arena + (size_t)(row0 + row) * astride + koff + sb * 16;
            __builtin_amdgcn_global_load_lds(AS1(ga), AS3(&ldsA[16384 + i * 4096 + t * 16]), 16, 0, 0);
        }
    };
    auto stageB_full = [&](int buf, int nc, int koff) {
        #pragma unroll
        for (int i = 0; i < 4; ++i) {
            int row = i * 32 + (t >> 3);
            int sb  = (t & 7) ^ (row & 7);
            const char* gb = Wb + (size_t)(nc * 128 + row) * astride + koff + sb * 16;
            __builtin_amdgcn_global_load_lds(AS1(gb), AS3(&ldsB[buf][i * 4096 + t * 16]), 16, 0, 0);
        }
    };
    auto stageB_half = [&](int buf, int nc, int koff) {
        #pragma unroll
        for (int i = 0; i < 2; ++i) {
            int row = i * 64 + (t >> 2);
            int sb  = (t & 3) ^ (row & 3);
            const char* gb = Wb + (size_t)(nc * 128 + row) * astride + koff + sb * 16;
            __builtin_amdgcn_global_load_lds(AS1(gb), AS3(&ldsB[buf][i * 4096 + t * 16]), 16, 0, 0);
        }
    };

    if (z == 0) { stageA_full(0, 0); stageA_full(1, 128); stageA_full(2, 256); }
    else        { stageA_full(0, 0); stageA_half(128); }
    stageB_full(0, 0, 0);
    if (z == 0) stageB_full(1, 0, 128); else stageB_half(1, 0, 128);
    __syncthreads();

    int posr[16];
    #pragma unroll
    for (int m = 0; m < 4; ++m)
        #pragma unroll
        for (int j = 0; j < 4; ++j) {
            int gr = row0 + wr * 64 + m * 16 + q * 4 + j;
            posr[m * 4 + j] = (gr < count) ? posm[gr] : -1;
        }

    f32x4 acc[4][4];
    auto compA_full = [&](int ktA, int buf) {
        #pragma unroll
        for (int kk = 0; kk < 4; ++kk) {
            const int u  = kk * 2 + (q >> 1);
            const int wo = (q & 1) * 8;
            long af[4], bf[4];
            #pragma unroll
            for (int m = 0; m < 4; ++m) {
                int arow = wr * 64 + m * 16 + r;
                af[m] = *reinterpret_cast<const long*>(
                    &ldsA[ktA * 16384 + arow * 128 + ((u ^ (arow & 7)) << 4) + wo]);
            }
            #pragma unroll
            for (int n = 0; n < 4; ++n) {
                int brow = wc * 64 + n * 16 + r;
                bf[n] = *reinterpret_cast<const long*>(
                    &ldsB[buf][brow * 128 + ((u ^ (brow & 7)) << 4) + wo]);
            }
            #pragma unroll
            for (int m = 0; m < 4; ++m)
                #pragma unroll
                for (int n = 0; n < 4; ++n)
                    acc[m][n] = __builtin_amdgcn_mfma_f32_16x16x32_fp8_fp8(af[m], bf[n], acc[m][n], 0, 0, 0);
        }
    };
    auto compA_half = [&](int buf) {
        #pragma unroll
        for (int kk = 0; kk < 2; ++kk) {
            const int u  = kk * 2 + (q >> 1);
            const int wo = (q & 1) * 8;
            long af[4], bf[4];
            #pragma unroll
            for (int m = 0; m < 4; ++m) {
                int arow = wr * 64 + m * 16 + r;
                af[m] = *reinterpret_cast<const long*>(
                    &ldsA[16384 + arow * 64 + ((u ^ (arow & 3)) << 4) + wo]);
            }
            #pragma unroll
            for (int n = 0; n < 4; ++n) {
                int brow = wc * 64 + n * 16 + r;
                bf[n] = *reinterpret_cast<const long*>(
                    &ldsB[buf][brow * 64 + ((u ^ (brow & 3)) << 4) + wo]);
            }
            #pragma unroll
            for (int m = 0; m < 4; ++m)
                #pragma unroll
                for (int n = 0; n < 4; ++n)
                    acc[m][n] = __builtin_amdgcn_mfma_f32_16x16x32_fp8_fp8(af[m], bf[n], acc[m][n], 0, 0, 0);
        }
    };
    auto epilogue = [&](int nc) {
        float bv[4];
        #pragma unroll
        for (int n = 0; n < 4; ++n) bv[n] = bias[nc * 128 + wc * 64 + n * 16 + r];
        #pragma unroll
        for (int m = 0; m < 4; ++m)
            #pragma unroll
            for (int j = 0; j < 4; ++j) {
                int pos = posr[m * 4 + j];
                if (pos >= 0) {
                    float* orow = out + (size_t)pos * 512 + nc * 128 + wc * 64;
                    #pragma unroll
                    for (int n = 0; n < 4; ++n)
                        __builtin_nontemporal_store(
                            fmaxf(acc[m][n][j] * INV4096 + bv[n], 0.f), &orow[n * 16 + r]);
                }
            }
    };

    if (z == 0) {
        for (int nc = 0; nc < 4; ++nc) {
            #pragma unroll
            for (int m = 0; m < 4; ++m)
                #pragma unroll
                for (int n = 0; n < 4; ++n)
                    acc[m][n] = (f32x4){0.f, 0.f, 0.f, 0.f};
            #pragma unroll
            for (int kt = 0; kt < 3; ++kt) {
                int j = nc * 3 + kt, jn = j + 1;
                if (jn < 12) stageB_full(jn & 1, jn / 3, (jn % 3) * 128);
                compA_full(kt, j & 1);
                __syncthreads();
            }
            epilogue(nc);
        }
    } else {
        for (int nc = 0; nc < 4; ++nc) {
            #pragma unroll
            for (int m = 0; m < 4; ++m)
                #pragma unroll
                for (int n = 0; n < 4; ++n)
                    acc[m][n] = (f32x4){0.f, 0.f, 0.f, 0.f};
            #pragma unroll
            for (int kt = 0; kt < 2; ++kt) {
                int j = nc * 2 + kt, jn = j + 1;
                if (jn < 8) {
                    if ((jn & 1) == 0) stageB_full(jn & 1, jn / 2, 0);
                    else               stageB_half(jn & 1, jn / 2, 128);
                }
                if (kt == 0) compA_full(0, j & 1);
                else         compA_half(j & 1);
                __syncthreads();
            }
            epilogue(nc);
        }
    }
}

// ---------------- host ----------------
extern "C" void kernel_launch(void* const* d_in, const int* in_sizes, int n_in,
                              void* d_out, int out_size, void* d_ws, size_t ws_size,
                              hipStream_t stream) {
    const float* ev_t    = (const float*)d_in[0];
    const float* word_t  = (const float*)d_in[1];
    const float* sku_t   = (const float*)d_in[2];
    const float* cat_t   = (const float*)d_in[3];
    const float* price_t = (const float*)d_in[4];
    const float* url_t   = (const float*)d_in[5];
    const float* sku_w   = (const float*)d_in[6];
    const float* sku_b   = (const float*)d_in[7];
    const float* url_w   = (const float*)d_in[8];
    const float* url_b   = (const float*)d_in[9];
    const float* query_w = (const float*)d_in[10];
    const float* query_b = (const float*)d_in[11];
    const int* event_type = (const int*)d_in[12];
    const int* sku_id     = (const int*)d_in[13];
    const int* url_id     = (const int*)d_in[14];
    const int* cat_id     = (const int*)d_in[15];
    const int* price_id   = (const int*)d_in[16];
    const int* word_id    = (const int*)d_in[17];

    char*  ws  = (char*)d_ws;
    float* out = (float*)d_out;

    prep_k<<<7786, 256, 0, stream>>>(sku_w, url_w, query_w, word_t, ws);
    alloc_k<<<256, 256, 0, stream>>>(event_type, out, ws);
    dim3 gb(4096, 1, 3);
    build_k<<<gb, 256, 0, stream>>>(ev_t, sku_t, cat_t, price_t, url_t,
                                    event_type, sku_id, url_id, cat_id, price_id,
                                    word_id, ws);
    dim3 gg(512, 1, 3);
    gemm2_k<<<gg, 256, 0, stream>>>(ws, sku_b, url_b, query_b, out);
}